// Round 10
// baseline (376.368 us; speedup 1.0000x reference)
//
#include <hip/hip_runtime.h>

#define N_NODES 50000
#define N_EDGES 800000
#define D 128
#define NLAYERS 3
#define N_CLASSES 10
#define NUM_GRAPHS 256
#define BN_EPS 1e-5f

#define CHUNKS 64
#define CHSIZE 12500   // CHUNKS*CHSIZE == N_EDGES
#define RANGES 4
#define RSIZE 12500    // RANGES*RSIZE == N_NODES
#define SBANKS 8       // stats replication banks
#define NBLK 196       // node blocks of 256
#define UP 136         // padded LDS row stride (bf16): 128+8 -> bank-conflict-free-ish

typedef __attribute__((ext_vector_type(4))) float f4;
typedef __attribute__((ext_vector_type(2))) float f2;
typedef __attribute__((ext_vector_type(4))) int i4;
typedef __attribute__((ext_vector_type(8))) short short8;
typedef __attribute__((ext_vector_type(4))) unsigned short us4;
typedef __attribute__((ext_vector_type(8))) unsigned short us8;

__device__ inline float b2f(unsigned short u) {
    unsigned int i = ((unsigned int)u) << 16;
    return __builtin_bit_cast(float, i);
}
__device__ inline unsigned short f2b(float f) {
    unsigned int u = __builtin_bit_cast(unsigned int, f);
    unsigned int r = (u + 0x7FFFu + ((u >> 16) & 1u)) >> 16;  // RNE
    return (unsigned short)r;
}

// BN coef into LDS from banked stats: ac[0..127]=a, ac[128..255]=c (z_norm = a*z + c)
__device__ inline void coef_to_lds(const float* __restrict__ stats,
                                   const float* __restrict__ g,
                                   const float* __restrict__ bt,
                                   float* ac_sm, int tid) {
    if (tid < D) {
        float s = 0.f, q = 0.f;
#pragma unroll
        for (int b = 0; b < SBANKS; b++) {
            s += stats[b * 2 * D + tid];
            q += stats[b * 2 * D + D + tid];
        }
        float mu = s * (1.0f / N_NODES);
        float var = q * (1.0f / N_NODES) - mu * mu;
        float inv = rsqrtf(var + BN_EPS);
        float a = g[tid] * inv;
        ac_sm[tid] = a;
        ac_sm[D + tid] = bt[tid] - mu * a;
    }
}

// ---------------- graph build: LDS-partitioned histogram ----------------

__global__ __launch_bounds__(256) void k_ph(const int* __restrict__ dst,
                                            unsigned short* __restrict__ pos,
                                            unsigned short* __restrict__ ph) {
    __shared__ int h[RSIZE];
    int c = blockIdx.x, r = blockIdx.y;
    int t = threadIdx.x;
    for (int i = t; i < RSIZE; i += 256) h[i] = 0;
    __syncthreads();
    int base = c * CHSIZE;
    int lo = r * RSIZE;
    const i4* dst4 = (const i4*)(dst + base);
    for (int j = t; j < CHSIZE / 4; j += 256) {
        i4 dv = dst4[j];
#pragma unroll
        for (int u = 0; u < 4; u++) {
            int d = dv[u] - lo;
            if ((unsigned)d < RSIZE) pos[base + j * 4 + u] = (unsigned short)atomicAdd(&h[d], 1);
        }
    }
    __syncthreads();
    unsigned short* outp = ph + (size_t)c * N_NODES + lo;
    for (int i = t; i < RSIZE; i += 256) outp[i] = (unsigned short)h[i];
}

// fused: chunk prefix + deg + block sums + graph boundaries + degree histogram
__global__ __launch_bounds__(256) void k_m1(unsigned short* __restrict__ ph,
                                            const int* __restrict__ bat,
                                            int* __restrict__ deg,
                                            int* __restrict__ bsum,
                                            int* __restrict__ gp,
                                            int* __restrict__ bh) {
    __shared__ int sm[256];
    __shared__ int hist[64];
    int t = threadIdx.x;
    if (t < 64) hist[t] = 0;
    int b = blockIdx.x * 256 + t;
    int s = 0;
    if (b < N_NODES) {
#pragma unroll 4
        for (int c = 0; c < CHUNKS; c++) {
            int v = ph[(size_t)c * N_NODES + b];
            ph[(size_t)c * N_NODES + b] = (unsigned short)s;
            s += v;
        }
        deg[b] = s;
    }
    sm[t] = s;
    __syncthreads();  // covers hist zero too
    if (b < N_NODES) atomicAdd(&hist[min(s, 63)], 1);
    for (int off = 128; off > 0; off >>= 1) {
        if (t < off) sm[t] += sm[t + off];
        __syncthreads();
    }
    if (t == 0) bsum[blockIdx.x] = sm[0];
    if (t < 64) bh[blockIdx.x * 64 + t] = hist[t];
    if (b < N_NODES) {
        int bb = bat[b];
        int prev = (b == 0) ? -1 : bat[b - 1];
        for (int g = prev + 1; g <= bb; g++) gp[g] = b;
        if (b == N_NODES - 1)
            for (int g = bb + 1; g <= NUM_GRAPHS; g++) gp[g] = N_NODES;
    }
}

// ---------------- streaming prep: xcast + wprep ----------------

__global__ __launch_bounds__(256) void k_xw(const float* __restrict__ x,
                                            const float* __restrict__ W1,
                                            const float* __restrict__ W2,
                                            us4* __restrict__ xb,
                                            short8* __restrict__ Wb) {
    int gid = blockIdx.x * 256 + threadIdx.x;
    const f4* xf = (const f4*)x;
#pragma unroll
    for (int rep = 0; rep < 2; rep++) {
        int i = gid + rep * 800000;  // 2*800000 == N_NODES*D/4
        f4 v = xf[i];
        us4 o;
        o[0] = f2b(v.x); o[1] = f2b(v.y); o[2] = f2b(v.z); o[3] = f2b(v.w);
        xb[i] = o;
    }
    if (gid < 6 * 32 * 64) {
        int m = gid >> 11;
        int f = (gid >> 6) & 31;
        int l = gid & 63;
        int ct = f >> 2, ks = f & 3;
        int n = ct * 16 + (l & 15);
        int k0 = ks * 32 + (l >> 4) * 8;
        const float* Wsrc = (m < 3) ? (W1 + (size_t)m * D * D) : (W2 + (size_t)(m - 3) * D * D);
        short8 o;
#pragma unroll
        for (int j = 0; j < 8; j++) o[j] = (short)f2b(Wsrc[(size_t)(k0 + j) * D + n]);
        Wb[gid] = o;
    }
}

// ---------------- scan level 2: bsum scan + degree-bucket bases ----------------

__global__ void k_s2(int* __restrict__ bsum, int* __restrict__ rowp, int* __restrict__ bh) {
    __shared__ int sm[256];
    int t = threadIdx.x;  // 256
    int v = (t < NBLK) ? bsum[t] : 0;
    sm[t] = v;
    __syncthreads();
    for (int off = 1; off < 256; off <<= 1) {
        int u = (t >= off) ? sm[t - off] : 0;
        __syncthreads();
        sm[t] += u;
        __syncthreads();
    }
    if (t < NBLK) bsum[t] = sm[t] - v;
    if (t == NBLK - 1) rowp[N_NODES] = sm[t];
    __syncthreads();
    // degree-bucket global bases
    int tot = 0;
    if (t < 64) {
        for (int blk = 0; blk < NBLK; blk++) tot += bh[blk * 64 + t];
    }
    sm[t] = (t < 64) ? tot : 0;
    __syncthreads();
    for (int off = 1; off < 64; off <<= 1) {
        int u = (t >= off && t < 64) ? sm[t - off] : 0;
        __syncthreads();
        if (t < 64) sm[t] += u;
        __syncthreads();
    }
    if (t < 64) {
        int run = sm[t] - tot;  // exclusive bucket base
        for (int blk = 0; blk < NBLK; blk++) {
            int tmp = bh[blk * 64 + t];
            bh[blk * 64 + t] = run;
            run += tmp;
        }
    }
}

// ---------------- scan level 3: rowp + degree-sort permutation ----------------

__global__ void k_s3(const int* __restrict__ deg, const int* __restrict__ bsum,
                     int* __restrict__ rowp, const int* __restrict__ bh,
                     unsigned short* __restrict__ perm) {
    __shared__ int sm[256];
    __shared__ int lh[64];
    int t = threadIdx.x;
    if (t < 64) lh[t] = 0;
    int i = blockIdx.x * 256 + t;
    int v = (i < N_NODES) ? deg[i] : 0;
    sm[t] = v;
    __syncthreads();
    for (int off = 1; off < 256; off <<= 1) {
        int u = (t >= off) ? sm[t - off] : 0;
        __syncthreads();
        sm[t] += u;
        __syncthreads();
    }
    if (i < N_NODES) {
        rowp[i] = bsum[blockIdx.x] + sm[t] - v;
        int bk = min(v, 63);
        int p = atomicAdd(&lh[bk], 1);
        perm[bh[blockIdx.x * 64 + bk] + p] = (unsigned short)i;
    }
}

// atomic-free scatter into ushort csr
__global__ __launch_bounds__(256) void k_scatter(const int* __restrict__ src,
                                                 const int* __restrict__ dst,
                                                 const unsigned short* __restrict__ pos,
                                                 const unsigned short* __restrict__ ph,
                                                 const int* __restrict__ rowp,
                                                 unsigned short* __restrict__ csr) {
    int e0 = (blockIdx.x * 256 + threadIdx.x) * 4;
    if (e0 >= N_EDGES) return;  // N_EDGES % 4 == 0
    int cc = e0 / CHSIZE;       // CHSIZE % 4 == 0 -> whole quad in one chunk
    i4 sv = *(const i4*)(src + e0);
    i4 dv = *(const i4*)(dst + e0);
    us4 pv = *(const us4*)(pos + e0);
    const unsigned short* phc = ph + (size_t)cc * N_NODES;
#pragma unroll
    for (int u = 0; u < 4; u++) {
        int d = dv[u];
        csr[rowp[d] + (int)phc[d] + (int)pv[u]] = (unsigned short)sv[u];
    }
}

// ---------------- fused gather + GEMM1: z1 = (t(h)self + sum t(h)nbr) @ W1 + b1 ----------------
// block: 128 perm-ordered nodes; gather into LDS u; MFMA from LDS; scatter z1 to node rows.

template <bool APPLY_T>
__global__ __launch_bounds__(256) void k_ag(const us8* __restrict__ H,
                                            const float* __restrict__ stats,
                                            const float* __restrict__ g,
                                            const float* __restrict__ bt,
                                            const int* __restrict__ rowp,
                                            const unsigned short* __restrict__ csr,
                                            const unsigned short* __restrict__ perm,
                                            const short8* __restrict__ Wb,
                                            const float* __restrict__ bias,
                                            unsigned short* __restrict__ Z,
                                            float* __restrict__ stats_out) {
    __shared__ unsigned short u[128][UP];
    __shared__ float ac_sm[2 * D];
    __shared__ float lds_s[D], lds_q[D];
    int tid = threadIdx.x;
    if (tid < D) { lds_s[tid] = 0.f; lds_q[tid] = 0.f; }
    if (APPLY_T) coef_to_lds(stats, g, bt, ac_sm, tid);
    __syncthreads();

    // ---- gather phase: 8 rounds x 16 nodes, 16 lanes/node ----
    int slot = tid >> 4, lane = tid & 15;
    int base = blockIdx.x * 128;
    float av[8], cv[8];
    if (APPLY_T) {
#pragma unroll
        for (int i = 0; i < 8; i++) {
            av[i] = ac_sm[lane * 8 + i];
            cv[i] = ac_sm[D + lane * 8 + i];
        }
    }
    for (int ns = 0; ns < 8; ns++) {
        int li = base + ns * 16 + slot;
        int node = perm[li < N_NODES ? li : N_NODES - 1];
        float s[8] = {0.f, 0.f, 0.f, 0.f, 0.f, 0.f, 0.f, 0.f};
        auto accum = [&](us8 v) {
#pragma unroll
            for (int i = 0; i < 8; i++) {
                float f = b2f(v[i]);
                if (APPLY_T) f = fmaxf(f * av[i] + cv[i], 0.f);
                s[i] += f;
            }
        };
        accum(H[(size_t)node * 16 + lane]);  // self
        int beg = rowp[node], end = rowp[node + 1];
        int j = beg;
        for (; j + 8 <= end; j += 8) {
            int idx[8];
#pragma unroll
            for (int q = 0; q < 8; q++) idx[q] = csr[j + q];
            us8 v[8];
#pragma unroll
            for (int q = 0; q < 8; q++) v[q] = H[(size_t)idx[q] * 16 + lane];
#pragma unroll
            for (int q = 0; q < 8; q++) accum(v[q]);
        }
        for (; j + 2 <= end; j += 2) {
            int i0 = csr[j], i1 = csr[j + 1];
            us8 v0 = H[(size_t)i0 * 16 + lane];
            us8 v1 = H[(size_t)i1 * 16 + lane];
            accum(v0); accum(v1);
        }
        if (j < end) accum(H[(size_t)csr[j] * 16 + lane]);
        us8 o;
#pragma unroll
        for (int i = 0; i < 8; i++) o[i] = f2b(s[i]);
        *(us8*)&u[ns * 16 + slot][lane * 8] = o;
    }
    __syncthreads();

    // ---- GEMM phase: A from LDS ----
    int w = tid >> 6, l = tid & 63;
    int lr = l & 15, lg = l >> 4;
    int rowb0 = w * 32;
    f4 acc[2][8];
#pragma unroll
    for (int ct = 0; ct < 8; ct++) {
        float bv = bias[ct * 16 + lr];
#pragma unroll
        for (int rt = 0; rt < 2; rt++) {
            acc[rt][ct].x = bv; acc[rt][ct].y = bv; acc[rt][ct].z = bv; acc[rt][ct].w = bv;
        }
    }
#pragma unroll
    for (int ks = 0; ks < 4; ks++) {
        int k0 = ks * 32 + lg * 8;
        short8 a[2];
#pragma unroll
        for (int rt = 0; rt < 2; rt++)
            a[rt] = *(const short8*)&u[rowb0 + rt * 16 + lr][k0];
#pragma unroll
        for (int ct = 0; ct < 8; ct++) {
            short8 b = Wb[(ct * 4 + ks) * 64 + l];
            acc[0][ct] = __builtin_amdgcn_mfma_f32_16x16x32_bf16(a[0], b, acc[0][ct], 0, 0, 0);
            acc[1][ct] = __builtin_amdgcn_mfma_f32_16x16x32_bf16(a[1], b, acc[1][ct], 0, 0, 0);
        }
    }

    // ---- epilogue: scatter to node rows + banked stats ----
    float vm[2][4];
    int nrow[2][4];
#pragma unroll
    for (int rt = 0; rt < 2; rt++)
#pragma unroll
        for (int r = 0; r < 4; r++) {
            int gi = base + rowb0 + rt * 16 + lg * 4 + r;
            bool ok = gi < N_NODES;
            vm[rt][r] = ok ? 1.f : 0.f;
            nrow[rt][r] = ok ? (int)perm[gi] : 0;
        }
#pragma unroll
    for (int ct = 0; ct < 8; ct++) {
        float s = 0.f, q = 0.f;
#pragma unroll
        for (int rt = 0; rt < 2; rt++) {
#pragma unroll
            for (int r = 0; r < 4; r++) {
                float v = acc[rt][ct][r];
                s += v * vm[rt][r];
                q += v * v * vm[rt][r];
                if (vm[rt][r] != 0.f)
                    Z[(size_t)nrow[rt][r] * D + ct * 16 + lr] = f2b(v);
            }
        }
        s += __shfl_xor(s, 16);
        s += __shfl_xor(s, 32);
        q += __shfl_xor(q, 16);
        q += __shfl_xor(q, 32);
        if (lg == 0) {
            atomicAdd(&lds_s[ct * 16 + lr], s);
            atomicAdd(&lds_q[ct * 16 + lr], q);
        }
    }
    __syncthreads();
    int bank = blockIdx.x & (SBANKS - 1);
    if (tid < D) {
        atomicAdd(&stats_out[bank * 2 * D + tid], lds_s[tid]);
        atomicAdd(&stats_out[bank * 2 * D + D + tid], lds_q[tid]);
    }
}

// ---------------- MFMA GEMM2: h = relu(bn1(z1)) @ W2 + b2, fused banked stats ----------------

__global__ __launch_bounds__(256) void k_gemm2(const unsigned short* __restrict__ A,
                                               const short8* __restrict__ Wb,
                                               const float* __restrict__ bias,
                                               const float* __restrict__ stats_in,
                                               const float* __restrict__ g,
                                               const float* __restrict__ bt,
                                               unsigned short* __restrict__ Z,
                                               float* __restrict__ stats_out, int M) {
    __shared__ float lds_s[D], lds_q[D];
    __shared__ float ac_sm[2 * D];
    int tid = threadIdx.x;
    if (tid < D) { lds_s[tid] = 0.f; lds_q[tid] = 0.f; }
    coef_to_lds(stats_in, g, bt, ac_sm, tid);
    int w = tid >> 6, l = tid & 63;
    int lr = l & 15, lg = l >> 4;
    int rowb0 = blockIdx.x * 128 + w * 32;
    f4 acc[2][8];
#pragma unroll
    for (int ct = 0; ct < 8; ct++) {
        float bv = bias[ct * 16 + lr];
#pragma unroll
        for (int rt = 0; rt < 2; rt++) {
            acc[rt][ct].x = bv; acc[rt][ct].y = bv; acc[rt][ct].z = bv; acc[rt][ct].w = bv;
        }
    }
    __syncthreads();

#pragma unroll
    for (int ks = 0; ks < 4; ks++) {
        short8 a[2];
#pragma unroll
        for (int rt = 0; rt < 2; rt++) {
            int arow = rowb0 + rt * 16 + lr;
            int arow_c = arow < M ? arow : M - 1;
            int k0 = ks * 32 + lg * 8;
            const unsigned short* ap = A + (size_t)arow_c * D + k0;
            us4 v0 = *(const us4*)ap;
            us4 v1 = *(const us4*)(ap + 4);
            f4 a0 = *(const f4*)&ac_sm[k0];
            f4 a1 = *(const f4*)&ac_sm[k0 + 4];
            f4 c0 = *(const f4*)&ac_sm[D + k0];
            f4 c1 = *(const f4*)&ac_sm[D + k0 + 4];
            a[rt][0] = (short)f2b(fmaxf(b2f(v0[0]) * a0.x + c0.x, 0.f));
            a[rt][1] = (short)f2b(fmaxf(b2f(v0[1]) * a0.y + c0.y, 0.f));
            a[rt][2] = (short)f2b(fmaxf(b2f(v0[2]) * a0.z + c0.z, 0.f));
            a[rt][3] = (short)f2b(fmaxf(b2f(v0[3]) * a0.w + c0.w, 0.f));
            a[rt][4] = (short)f2b(fmaxf(b2f(v1[0]) * a1.x + c1.x, 0.f));
            a[rt][5] = (short)f2b(fmaxf(b2f(v1[1]) * a1.y + c1.y, 0.f));
            a[rt][6] = (short)f2b(fmaxf(b2f(v1[2]) * a1.z + c1.z, 0.f));
            a[rt][7] = (short)f2b(fmaxf(b2f(v1[3]) * a1.w + c1.w, 0.f));
        }
#pragma unroll
        for (int ct = 0; ct < 8; ct++) {
            short8 b = Wb[(ct * 4 + ks) * 64 + l];
            acc[0][ct] = __builtin_amdgcn_mfma_f32_16x16x32_bf16(a[0], b, acc[0][ct], 0, 0, 0);
            acc[1][ct] = __builtin_amdgcn_mfma_f32_16x16x32_bf16(a[1], b, acc[1][ct], 0, 0, 0);
        }
    }

#pragma unroll
    for (int ct = 0; ct < 8; ct++) {
        float s = 0.f, q = 0.f;
#pragma unroll
        for (int rt = 0; rt < 2; rt++) {
#pragma unroll
            for (int r = 0; r < 4; r++) {
                float v = acc[rt][ct][r];
                int rd = rowb0 + rt * 16 + lg * 4 + r;
                float m = rd < M ? 1.f : 0.f;
                s += v * m;
                q += v * v * m;
                if (rd < M) Z[(size_t)rd * D + ct * 16 + lr] = f2b(v);
            }
        }
        s += __shfl_xor(s, 16);
        s += __shfl_xor(s, 32);
        q += __shfl_xor(q, 16);
        q += __shfl_xor(q, 32);
        if (lg == 0) {
            atomicAdd(&lds_s[ct * 16 + lr], s);
            atomicAdd(&lds_q[ct * 16 + lr], q);
        }
    }
    __syncthreads();
    int bank = blockIdx.x & (SBANKS - 1);
    if (tid < D) {
        atomicAdd(&stats_out[bank * 2 * D + tid], lds_s[tid]);
        atomicAdd(&stats_out[bank * 2 * D + D + tid], lds_q[tid]);
    }
}

// ---------------- readout ----------------

__global__ __launch_bounds__(256) void k_readout(const unsigned int* __restrict__ Zb,
                                                 const float* __restrict__ stats,
                                                 const float* __restrict__ g,
                                                 const float* __restrict__ bt,
                                                 const int* __restrict__ gp,
                                                 const int* __restrict__ batch,
                                                 float* __restrict__ ro, int layer) {
    __shared__ f2 sm[256];
    __shared__ float ac_sm[2 * D];
    int tid = threadIdx.x;
    coef_to_lds(stats, g, bt, ac_sm, tid);
    __syncthreads();
    int n0 = blockIdx.x * 256;
    int n1 = n0 + 256; if (n1 > N_NODES) n1 = N_NODES;
    int g_lo = batch[n0], g_hi = batch[n1 - 1];
    int grp = tid >> 6, cw = tid & 63;
    float a0 = ac_sm[2 * cw], a1 = ac_sm[2 * cw + 1];
    float c0 = ac_sm[D + 2 * cw], c1 = ac_sm[D + 2 * cw + 1];
    for (int gg = g_lo; gg <= g_hi; gg++) {
        int beg = gp[gg]; if (beg < n0) beg = n0;
        int end = gp[gg + 1]; if (end > n1) end = n1;
        f2 acc; acc.x = 0.f; acc.y = 0.f;
        for (int r = beg + grp; r < end; r += 4) {
            unsigned int v = Zb[(size_t)r * 64 + cw];
            float x0 = b2f((unsigned short)(v & 0xFFFFu));
            float x1 = b2f((unsigned short)(v >> 16));
            acc.x += fmaxf(x0 * a0 + c0, 0.f);
            acc.y += fmaxf(x1 * a1 + c1, 0.f);
        }
        sm[tid] = acc;
        __syncthreads();
        if (tid < 64) {
            f2 t = sm[tid];
            t.x += sm[tid + 64].x + sm[tid + 128].x + sm[tid + 192].x;
            t.y += sm[tid + 64].y + sm[tid + 128].y + sm[tid + 192].y;
            atomicAdd(&ro[(size_t)gg * (NLAYERS * D) + layer * D + 2 * cw], t.x);
            atomicAdd(&ro[(size_t)gg * (NLAYERS * D) + layer * D + 2 * cw + 1], t.y);
        }
        __syncthreads();
    }
}

// ---------------- classifier ----------------

__global__ void k_cls(const float* __restrict__ ro, const float* __restrict__ Wc1,
                      const float* __restrict__ bc1, const float* __restrict__ Wc2,
                      const float* __restrict__ bc2, float* __restrict__ out) {
    __shared__ float r_sm[NLAYERS * D];
    __shared__ float h_sm[D];
    int g = blockIdx.x;
    int t = threadIdx.x;  // 128
    for (int i = t; i < NLAYERS * D; i += D) r_sm[i] = ro[(size_t)g * (NLAYERS * D) + i];
    __syncthreads();
    float acc = bc1[t];
    for (int k = 0; k < NLAYERS * D; k++) acc += r_sm[k] * Wc1[(size_t)k * D + t];
    h_sm[t] = fmaxf(acc, 0.f);
    __syncthreads();
    if (t < N_CLASSES) {
        float o = bc2[t];
        for (int k = 0; k < D; k++) o += h_sm[k] * Wc2[k * N_CLASSES + t];
        out[g * N_CLASSES + t] = o;
    }
}

// ---------------- launch ----------------

extern "C" void kernel_launch(void* const* d_in, const int* in_sizes, int n_in,
                              void* d_out, int out_size, void* d_ws, size_t ws_size,
                              hipStream_t stream) {
    const float* x   = (const float*)d_in[0];
    const int*   ei  = (const int*)d_in[1];
    const int*   bat = (const int*)d_in[2];
    const float* W1  = (const float*)d_in[3];
    const float* b1  = (const float*)d_in[4];
    const float* g1  = (const float*)d_in[5];
    const float* bt1 = (const float*)d_in[6];
    const float* W2  = (const float*)d_in[7];
    const float* b2  = (const float*)d_in[8];
    const float* g2  = (const float*)d_in[9];
    const float* bt2 = (const float*)d_in[10];
    const float* Wc1 = (const float*)d_in[11];
    const float* bc1 = (const float*)d_in[12];
    const float* Wc2 = (const float*)d_in[13];
    const float* bc2 = (const float*)d_in[14];
    float* out = (float*)d_out;

    const int* src = ei;
    const int* dst = ei + N_EDGES;

    char* ws = (char*)d_ws;
    size_t off = 0;
    auto alloc = [&](size_t bytes) -> void* {
        void* p = ws + off;
        off += (bytes + 255) & ~(size_t)255;
        return p;
    };
    // --- zero zone (single memset) ---
    float* stats = (float*)alloc(6 * SBANKS * 2 * D * sizeof(float));  // [6 BNs][banks][2D]
    float* ro    = (float*)alloc((size_t)NUM_GRAPHS * NLAYERS * D * sizeof(float));
    size_t zero_bytes = off;
    // --- rest (no init needed) ---
    int*   deg   = (int*)alloc(N_NODES * sizeof(int));
    int*   gp    = (int*)alloc((NUM_GRAPHS + 1) * sizeof(int));
    int*   bsum  = (int*)alloc(256 * sizeof(int));
    int*   rowp  = (int*)alloc((N_NODES + 1) * sizeof(int));
    int*   bh    = (int*)alloc(NBLK * 64 * sizeof(int));
    unsigned short* pos  = (unsigned short*)alloc(N_EDGES * sizeof(unsigned short));
    unsigned short* csr  = (unsigned short*)alloc(N_EDGES * sizeof(unsigned short));
    unsigned short* perm = (unsigned short*)alloc(N_NODES * sizeof(unsigned short));
    const size_t NBH = (size_t)N_NODES * D * sizeof(unsigned short);
    unsigned short* xb   = (unsigned short*)alloc(NBH);
    unsigned short* bufB = (unsigned short*)alloc(NBH);
    unsigned short* bufC = (unsigned short*)alloc(NBH);
    short8* Wb   = (short8*)alloc(6 * 32 * 64 * sizeof(short8));
    // ph scratch aliases bufB (6.4 MB < 12.8 MB); last use (k_scatter) precedes bufB's first write
    unsigned short* ph = (unsigned short*)bufB;

    hipMemsetAsync(ws, 0, zero_bytes, stream);

    k_ph<<<dim3(CHUNKS, RANGES), 256, 0, stream>>>(dst, pos, ph);
    k_m1<<<NBLK, 256, 0, stream>>>(ph, bat, deg, bsum, gp, bh);
    k_xw<<<3125, 256, 0, stream>>>(x, W1, W2, (us4*)xb, Wb);
    k_s2<<<1, 256, 0, stream>>>(bsum, rowp, bh);
    k_s3<<<NBLK, 256, 0, stream>>>(deg, bsum, rowp, bh, perm);
    k_scatter<<<(N_EDGES / 4 + 255) / 256, 256, 0, stream>>>(src, dst, pos, ph, rowp, csr);

    const int ag_grid   = (N_NODES + 127) / 128;  // 391
    const int gemm_grid = (N_NODES + 127) / 128;  // 391
    const unsigned short* H = xb;
    for (int i = 0; i < NLAYERS; i++) {
        float* st1 = stats + (size_t)(2 * i) * SBANKS * 2 * D;
        float* st2 = stats + (size_t)(2 * i + 1) * SBANKS * 2 * D;
        float* st2p = stats + (size_t)(2 * i - 1) * SBANKS * 2 * D;  // prev layer bn2
        if (i == 0)
            k_ag<false><<<ag_grid, 256, 0, stream>>>((const us8*)H, nullptr, nullptr, nullptr,
                                                     rowp, csr, perm, Wb + (size_t)i * 2048,
                                                     b1 + i * D, bufB, st1);
        else
            k_ag<true><<<ag_grid, 256, 0, stream>>>((const us8*)H, st2p, g2 + (i - 1) * D,
                                                    bt2 + (i - 1) * D, rowp, csr, perm,
                                                    Wb + (size_t)i * 2048, b1 + i * D, bufB, st1);
        k_gemm2<<<gemm_grid, 256, 0, stream>>>(bufB, Wb + (size_t)(3 + i) * 2048, b2 + i * D,
                                               st1, g1 + i * D, bt1 + i * D, bufC, st2, N_NODES);
        k_readout<<<NBLK, 256, 0, stream>>>((const unsigned int*)bufC, st2, g2 + i * D, bt2 + i * D,
                                            gp, bat, ro, i);
        H = bufC;
    }
    k_cls<<<NUM_GRAPHS, 128, 0, stream>>>(ro, Wc1, bc1, Wc2, bc2, out);
}

// Round 11
// 332.774 us; speedup vs baseline: 1.1310x; 1.1310x over previous
//
#include <hip/hip_runtime.h>

#define N_NODES 50000
#define N_EDGES 800000
#define D 128
#define NLAYERS 3
#define N_CLASSES 10
#define NUM_GRAPHS 256
#define BN_EPS 1e-5f

#define CHUNKS 64
#define CHSIZE 12500   // CHUNKS*CHSIZE == N_EDGES
#define RANGES 4
#define RSIZE 12500    // RANGES*RSIZE == N_NODES
#define SBANKS 8       // stats replication banks
#define NBLK 196       // node blocks of 256

typedef __attribute__((ext_vector_type(4))) float f4;
typedef __attribute__((ext_vector_type(2))) float f2;
typedef __attribute__((ext_vector_type(4))) int i4;
typedef __attribute__((ext_vector_type(8))) short short8;
typedef __attribute__((ext_vector_type(4))) unsigned short us4;
typedef __attribute__((ext_vector_type(8))) unsigned short us8;

__device__ inline float b2f(unsigned short u) {
    unsigned int i = ((unsigned int)u) << 16;
    return __builtin_bit_cast(float, i);
}
__device__ inline unsigned short f2b(float f) {
    unsigned int u = __builtin_bit_cast(unsigned int, f);
    unsigned int r = (u + 0x7FFFu + ((u >> 16) & 1u)) >> 16;  // RNE
    return (unsigned short)r;
}

// BN coef into LDS from banked stats: ac[0..127]=a, ac[128..255]=c (z_norm = a*z + c)
__device__ inline void coef_to_lds(const float* __restrict__ stats,
                                   const float* __restrict__ g,
                                   const float* __restrict__ bt,
                                   float* ac_sm, int tid) {
    if (tid < D) {
        float s = 0.f, q = 0.f;
#pragma unroll
        for (int b = 0; b < SBANKS; b++) {
            s += stats[b * 2 * D + tid];
            q += stats[b * 2 * D + D + tid];
        }
        float mu = s * (1.0f / N_NODES);
        float var = q * (1.0f / N_NODES) - mu * mu;
        float inv = rsqrtf(var + BN_EPS);
        float a = g[tid] * inv;
        ac_sm[tid] = a;
        ac_sm[D + tid] = bt[tid] - mu * a;
    }
}

// ---------------- graph build: LDS-partitioned histogram ----------------

__global__ __launch_bounds__(256) void k_ph(const int* __restrict__ dst,
                                            unsigned short* __restrict__ pos,
                                            unsigned short* __restrict__ ph) {
    __shared__ int h[RSIZE];
    int c = blockIdx.x, r = blockIdx.y;
    int t = threadIdx.x;
    for (int i = t; i < RSIZE; i += 256) h[i] = 0;
    __syncthreads();
    int base = c * CHSIZE;
    int lo = r * RSIZE;
    const i4* dst4 = (const i4*)(dst + base);
    for (int j = t; j < CHSIZE / 4; j += 256) {
        i4 dv = dst4[j];
#pragma unroll
        for (int u = 0; u < 4; u++) {
            int d = dv[u] - lo;
            if ((unsigned)d < RSIZE) pos[base + j * 4 + u] = (unsigned short)atomicAdd(&h[d], 1);
        }
    }
    __syncthreads();
    unsigned short* outp = ph + (size_t)c * N_NODES + lo;
    for (int i = t; i < RSIZE; i += 256) outp[i] = (unsigned short)h[i];
}

// fused: chunk prefix + deg + block sums + graph boundaries + degree histogram
__global__ __launch_bounds__(256) void k_m1(unsigned short* __restrict__ ph,
                                            const int* __restrict__ bat,
                                            int* __restrict__ deg,
                                            int* __restrict__ bsum,
                                            int* __restrict__ gp,
                                            int* __restrict__ bh) {
    __shared__ int sm[256];
    __shared__ int hist[64];
    int t = threadIdx.x;
    if (t < 64) hist[t] = 0;
    int b = blockIdx.x * 256 + t;
    int s = 0;
    if (b < N_NODES) {
#pragma unroll 4
        for (int c = 0; c < CHUNKS; c++) {
            int v = ph[(size_t)c * N_NODES + b];
            ph[(size_t)c * N_NODES + b] = (unsigned short)s;
            s += v;
        }
        deg[b] = s;
    }
    sm[t] = s;
    __syncthreads();  // covers hist zero too
    if (b < N_NODES) atomicAdd(&hist[min(s, 63)], 1);
    for (int off = 128; off > 0; off >>= 1) {
        if (t < off) sm[t] += sm[t + off];
        __syncthreads();
    }
    if (t == 0) bsum[blockIdx.x] = sm[0];
    if (t < 64) bh[blockIdx.x * 64 + t] = hist[t];
    if (b < N_NODES) {
        int bb = bat[b];
        int prev = (b == 0) ? -1 : bat[b - 1];
        for (int g = prev + 1; g <= bb; g++) gp[g] = b;
        if (b == N_NODES - 1)
            for (int g = bb + 1; g <= NUM_GRAPHS; g++) gp[g] = N_NODES;
    }
}

// ---------------- streaming prep: xcast + wprep ----------------

__global__ __launch_bounds__(256) void k_xw(const float* __restrict__ x,
                                            const float* __restrict__ W1,
                                            const float* __restrict__ W2,
                                            us4* __restrict__ xb,
                                            short8* __restrict__ Wb) {
    int gid = blockIdx.x * 256 + threadIdx.x;
    const f4* xf = (const f4*)x;
#pragma unroll
    for (int rep = 0; rep < 2; rep++) {
        int i = gid + rep * 800000;  // 2*800000 == N_NODES*D/4
        f4 v = xf[i];
        us4 o;
        o[0] = f2b(v.x); o[1] = f2b(v.y); o[2] = f2b(v.z); o[3] = f2b(v.w);
        xb[i] = o;
    }
    if (gid < 6 * 32 * 64) {
        int m = gid >> 11;
        int f = (gid >> 6) & 31;
        int l = gid & 63;
        int ct = f >> 2, ks = f & 3;
        int n = ct * 16 + (l & 15);
        int k0 = ks * 32 + (l >> 4) * 8;
        const float* Wsrc = (m < 3) ? (W1 + (size_t)m * D * D) : (W2 + (size_t)(m - 3) * D * D);
        short8 o;
#pragma unroll
        for (int j = 0; j < 8; j++) o[j] = (short)f2b(Wsrc[(size_t)(k0 + j) * D + n]);
        Wb[gid] = o;
    }
}

// ---------------- scan level 2: bsum scan + degree-bucket bases ----------------

__global__ void k_s2(int* __restrict__ bsum, int* __restrict__ rowp, int* __restrict__ bh) {
    __shared__ int sm[256];
    int t = threadIdx.x;  // 256
    int v = (t < NBLK) ? bsum[t] : 0;
    sm[t] = v;
    __syncthreads();
    for (int off = 1; off < 256; off <<= 1) {
        int u = (t >= off) ? sm[t - off] : 0;
        __syncthreads();
        sm[t] += u;
        __syncthreads();
    }
    if (t < NBLK) bsum[t] = sm[t] - v;
    if (t == NBLK - 1) rowp[N_NODES] = sm[t];
    __syncthreads();
    // degree-bucket global bases
    int tot = 0;
    if (t < 64) {
        for (int blk = 0; blk < NBLK; blk++) tot += bh[blk * 64 + t];
    }
    sm[t] = (t < 64) ? tot : 0;
    __syncthreads();
    for (int off = 1; off < 64; off <<= 1) {
        int u = (t >= off && t < 64) ? sm[t - off] : 0;
        __syncthreads();
        if (t < 64) sm[t] += u;
        __syncthreads();
    }
    if (t < 64) {
        int run = sm[t] - tot;  // exclusive bucket base
        for (int blk = 0; blk < NBLK; blk++) {
            int tmp = bh[blk * 64 + t];
            bh[blk * 64 + t] = run;
            run += tmp;
        }
    }
}

// ---------------- scan level 3: rowp + degree-sort permutation ----------------

__global__ void k_s3(const int* __restrict__ deg, const int* __restrict__ bsum,
                     int* __restrict__ rowp, const int* __restrict__ bh,
                     unsigned short* __restrict__ perm) {
    __shared__ int sm[256];
    __shared__ int lh[64];
    int t = threadIdx.x;
    if (t < 64) lh[t] = 0;
    int i = blockIdx.x * 256 + t;
    int v = (i < N_NODES) ? deg[i] : 0;
    sm[t] = v;
    __syncthreads();
    for (int off = 1; off < 256; off <<= 1) {
        int u = (t >= off) ? sm[t - off] : 0;
        __syncthreads();
        sm[t] += u;
        __syncthreads();
    }
    if (i < N_NODES) {
        rowp[i] = bsum[blockIdx.x] + sm[t] - v;
        int bk = min(v, 63);
        int p = atomicAdd(&lh[bk], 1);
        perm[bh[blockIdx.x * 64 + bk] + p] = (unsigned short)i;
    }
}

// atomic-free scatter into ushort csr
__global__ __launch_bounds__(256) void k_scatter(const int* __restrict__ src,
                                                 const int* __restrict__ dst,
                                                 const unsigned short* __restrict__ pos,
                                                 const unsigned short* __restrict__ ph,
                                                 const int* __restrict__ rowp,
                                                 unsigned short* __restrict__ csr) {
    int e0 = (blockIdx.x * 256 + threadIdx.x) * 4;
    if (e0 >= N_EDGES) return;  // N_EDGES % 4 == 0
    int cc = e0 / CHSIZE;       // CHSIZE % 4 == 0 -> whole quad in one chunk
    i4 sv = *(const i4*)(src + e0);
    i4 dv = *(const i4*)(dst + e0);
    us4 pv = *(const us4*)(pos + e0);
    const unsigned short* phc = ph + (size_t)cc * N_NODES;
#pragma unroll
    for (int u = 0; u < 4; u++) {
        int d = dv[u];
        csr[rowp[d] + (int)phc[d] + (int)pv[u]] = (unsigned short)sv[u];
    }
}

// ---------------- aggregation: 16 lanes/node, row-major, degree-sorted ----------------

template <bool APPLY_T>
__global__ __launch_bounds__(256) void k_agg(const us8* __restrict__ H,
                                             const float* __restrict__ stats,
                                             const float* __restrict__ g,
                                             const float* __restrict__ bt,
                                             const int* __restrict__ rowp,
                                             const unsigned short* __restrict__ csr,
                                             const unsigned short* __restrict__ perm,
                                             us8* __restrict__ U) {
    __shared__ float ac_sm[2 * D];
    int tid = threadIdx.x;
    if (APPLY_T) {
        coef_to_lds(stats, g, bt, ac_sm, tid);
        __syncthreads();
    }
    int gid = blockIdx.x * 256 + tid;
    int node = perm[gid >> 4];
    int lane = tid & 15;
    float av[8], cv[8];
    if (APPLY_T) {
#pragma unroll
        for (int i = 0; i < 8; i++) {
            av[i] = ac_sm[lane * 8 + i];
            cv[i] = ac_sm[D + lane * 8 + i];
        }
    }
    float s[8] = {0.f, 0.f, 0.f, 0.f, 0.f, 0.f, 0.f, 0.f};
    auto accum = [&](us8 v) {
#pragma unroll
        for (int i = 0; i < 8; i++) {
            float f = b2f(v[i]);
            if (APPLY_T) f = fmaxf(f * av[i] + cv[i], 0.f);
            s[i] += f;
        }
    };
    accum(H[(size_t)node * 16 + lane]);  // self
    int beg = rowp[node], end = rowp[node + 1];
    int j = beg;
    for (; j + 8 <= end; j += 8) {
        int idx[8];
#pragma unroll
        for (int u = 0; u < 8; u++) idx[u] = csr[j + u];
        us8 v[8];
#pragma unroll
        for (int u = 0; u < 8; u++) v[u] = H[(size_t)idx[u] * 16 + lane];
#pragma unroll
        for (int u = 0; u < 8; u++) accum(v[u]);
    }
    for (; j + 2 <= end; j += 2) {
        int i0 = csr[j], i1 = csr[j + 1];
        us8 v0 = H[(size_t)i0 * 16 + lane];
        us8 v1 = H[(size_t)i1 * 16 + lane];
        accum(v0); accum(v1);
    }
    if (j < end) accum(H[(size_t)csr[j] * 16 + lane]);
    us8 o;
#pragma unroll
    for (int i = 0; i < 8; i++) o[i] = f2b(s[i]);
    U[(size_t)node * 16 + lane] = o;
}

// ---------------- MFMA GEMM: 128 rows/block, fused banked column stats ----------------

template <bool TRANS>
__global__ __launch_bounds__(256) void k_gemm(const unsigned short* __restrict__ A,
                                              const short8* __restrict__ Wb,
                                              const float* __restrict__ bias,
                                              const float* __restrict__ stats_in,
                                              const float* __restrict__ g,
                                              const float* __restrict__ bt,
                                              unsigned short* __restrict__ Z,
                                              float* __restrict__ stats_out, int M) {
    __shared__ float lds_s[D], lds_q[D];
    __shared__ float ac_sm[2 * D];
    int tid = threadIdx.x;
    if (tid < D) { lds_s[tid] = 0.f; lds_q[tid] = 0.f; }
    if (TRANS) coef_to_lds(stats_in, g, bt, ac_sm, tid);
    int w = tid >> 6, l = tid & 63;
    int lr = l & 15, lg = l >> 4;
    int rowb0 = blockIdx.x * 128 + w * 32;
    f4 acc[2][8];
#pragma unroll
    for (int ct = 0; ct < 8; ct++) {
        float bv = bias[ct * 16 + lr];
#pragma unroll
        for (int rt = 0; rt < 2; rt++) {
            acc[rt][ct].x = bv; acc[rt][ct].y = bv; acc[rt][ct].z = bv; acc[rt][ct].w = bv;
        }
    }
    __syncthreads();

#pragma unroll
    for (int ks = 0; ks < 4; ks++) {
        short8 a[2];
#pragma unroll
        for (int rt = 0; rt < 2; rt++) {
            int arow = rowb0 + rt * 16 + lr;
            int arow_c = arow < M ? arow : M - 1;
            if (!TRANS) {
                a[rt] = *(const short8*)(A + (size_t)arow_c * D + ks * 32 + lg * 8);
            } else {
                int k0 = ks * 32 + lg * 8;
                const unsigned short* ap = A + (size_t)arow_c * D + k0;
                us4 v0 = *(const us4*)ap;
                us4 v1 = *(const us4*)(ap + 4);
                f4 a0 = *(const f4*)&ac_sm[k0];
                f4 a1 = *(const f4*)&ac_sm[k0 + 4];
                f4 c0 = *(const f4*)&ac_sm[D + k0];
                f4 c1 = *(const f4*)&ac_sm[D + k0 + 4];
                a[rt][0] = (short)f2b(fmaxf(b2f(v0[0]) * a0.x + c0.x, 0.f));
                a[rt][1] = (short)f2b(fmaxf(b2f(v0[1]) * a0.y + c0.y, 0.f));
                a[rt][2] = (short)f2b(fmaxf(b2f(v0[2]) * a0.z + c0.z, 0.f));
                a[rt][3] = (short)f2b(fmaxf(b2f(v0[3]) * a0.w + c0.w, 0.f));
                a[rt][4] = (short)f2b(fmaxf(b2f(v1[0]) * a1.x + c1.x, 0.f));
                a[rt][5] = (short)f2b(fmaxf(b2f(v1[1]) * a1.y + c1.y, 0.f));
                a[rt][6] = (short)f2b(fmaxf(b2f(v1[2]) * a1.z + c1.z, 0.f));
                a[rt][7] = (short)f2b(fmaxf(b2f(v1[3]) * a1.w + c1.w, 0.f));
            }
        }
#pragma unroll
        for (int ct = 0; ct < 8; ct++) {
            short8 b = Wb[(ct * 4 + ks) * 64 + l];
            acc[0][ct] = __builtin_amdgcn_mfma_f32_16x16x32_bf16(a[0], b, acc[0][ct], 0, 0, 0);
            acc[1][ct] = __builtin_amdgcn_mfma_f32_16x16x32_bf16(a[1], b, acc[1][ct], 0, 0, 0);
        }
    }

#pragma unroll
    for (int ct = 0; ct < 8; ct++) {
        float s = 0.f, q = 0.f;
#pragma unroll
        for (int rt = 0; rt < 2; rt++) {
#pragma unroll
            for (int r = 0; r < 4; r++) {
                float v = acc[rt][ct][r];
                int rd = rowb0 + rt * 16 + lg * 4 + r;
                float m = rd < M ? 1.f : 0.f;
                s += v * m;
                q += v * v * m;
                if (rd < M) Z[(size_t)rd * D + ct * 16 + lr] = f2b(v);
            }
        }
        s += __shfl_xor(s, 16);
        s += __shfl_xor(s, 32);
        q += __shfl_xor(q, 16);
        q += __shfl_xor(q, 32);
        if (lg == 0) {
            atomicAdd(&lds_s[ct * 16 + lr], s);
            atomicAdd(&lds_q[ct * 16 + lr], q);
        }
    }
    __syncthreads();
    int bank = blockIdx.x & (SBANKS - 1);
    if (tid < D) {
        atomicAdd(&stats_out[bank * 2 * D + tid], lds_s[tid]);
        atomicAdd(&stats_out[bank * 2 * D + D + tid], lds_q[tid]);
    }
}

// ---------------- readout ----------------

__global__ __launch_bounds__(256) void k_readout(const unsigned int* __restrict__ Zb,
                                                 const float* __restrict__ stats,
                                                 const float* __restrict__ g,
                                                 const float* __restrict__ bt,
                                                 const int* __restrict__ gp,
                                                 const int* __restrict__ batch,
                                                 float* __restrict__ ro, int layer) {
    __shared__ f2 sm[256];
    __shared__ float ac_sm[2 * D];
    int tid = threadIdx.x;
    coef_to_lds(stats, g, bt, ac_sm, tid);
    __syncthreads();
    int n0 = blockIdx.x * 256;
    int n1 = n0 + 256; if (n1 > N_NODES) n1 = N_NODES;
    int g_lo = batch[n0], g_hi = batch[n1 - 1];
    int grp = tid >> 6, cw = tid & 63;
    float a0 = ac_sm[2 * cw], a1 = ac_sm[2 * cw + 1];
    float c0 = ac_sm[D + 2 * cw], c1 = ac_sm[D + 2 * cw + 1];
    for (int gg = g_lo; gg <= g_hi; gg++) {
        int beg = gp[gg]; if (beg < n0) beg = n0;
        int end = gp[gg + 1]; if (end > n1) end = n1;
        f2 acc; acc.x = 0.f; acc.y = 0.f;
        for (int r = beg + grp; r < end; r += 4) {
            unsigned int v = Zb[(size_t)r * 64 + cw];
            float x0 = b2f((unsigned short)(v & 0xFFFFu));
            float x1 = b2f((unsigned short)(v >> 16));
            acc.x += fmaxf(x0 * a0 + c0, 0.f);
            acc.y += fmaxf(x1 * a1 + c1, 0.f);
        }
        sm[tid] = acc;
        __syncthreads();
        if (tid < 64) {
            f2 t = sm[tid];
            t.x += sm[tid + 64].x + sm[tid + 128].x + sm[tid + 192].x;
            t.y += sm[tid + 64].y + sm[tid + 128].y + sm[tid + 192].y;
            atomicAdd(&ro[(size_t)gg * (NLAYERS * D) + layer * D + 2 * cw], t.x);
            atomicAdd(&ro[(size_t)gg * (NLAYERS * D) + layer * D + 2 * cw + 1], t.y);
        }
        __syncthreads();
    }
}

// ---------------- classifier ----------------

__global__ void k_cls(const float* __restrict__ ro, const float* __restrict__ Wc1,
                      const float* __restrict__ bc1, const float* __restrict__ Wc2,
                      const float* __restrict__ bc2, float* __restrict__ out) {
    __shared__ float r_sm[NLAYERS * D];
    __shared__ float h_sm[D];
    int g = blockIdx.x;
    int t = threadIdx.x;  // 128
    for (int i = t; i < NLAYERS * D; i += D) r_sm[i] = ro[(size_t)g * (NLAYERS * D) + i];
    __syncthreads();
    float acc = bc1[t];
    for (int k = 0; k < NLAYERS * D; k++) acc += r_sm[k] * Wc1[(size_t)k * D + t];
    h_sm[t] = fmaxf(acc, 0.f);
    __syncthreads();
    if (t < N_CLASSES) {
        float o = bc2[t];
        for (int k = 0; k < D; k++) o += h_sm[k] * Wc2[k * N_CLASSES + t];
        out[g * N_CLASSES + t] = o;
    }
}

// ---------------- launch ----------------

extern "C" void kernel_launch(void* const* d_in, const int* in_sizes, int n_in,
                              void* d_out, int out_size, void* d_ws, size_t ws_size,
                              hipStream_t stream) {
    const float* x   = (const float*)d_in[0];
    const int*   ei  = (const int*)d_in[1];
    const int*   bat = (const int*)d_in[2];
    const float* W1  = (const float*)d_in[3];
    const float* b1  = (const float*)d_in[4];
    const float* g1  = (const float*)d_in[5];
    const float* bt1 = (const float*)d_in[6];
    const float* W2  = (const float*)d_in[7];
    const float* b2  = (const float*)d_in[8];
    const float* g2  = (const float*)d_in[9];
    const float* bt2 = (const float*)d_in[10];
    const float* Wc1 = (const float*)d_in[11];
    const float* bc1 = (const float*)d_in[12];
    const float* Wc2 = (const float*)d_in[13];
    const float* bc2 = (const float*)d_in[14];
    float* out = (float*)d_out;

    const int* src = ei;
    const int* dst = ei + N_EDGES;

    char* ws = (char*)d_ws;
    size_t off = 0;
    auto alloc = [&](size_t bytes) -> void* {
        void* p = ws + off;
        off += (bytes + 255) & ~(size_t)255;
        return p;
    };
    // --- zero zone (single memset) ---
    float* stats = (float*)alloc(6 * SBANKS * 2 * D * sizeof(float));  // [6 BNs][banks][2D]
    float* ro    = (float*)alloc((size_t)NUM_GRAPHS * NLAYERS * D * sizeof(float));
    size_t zero_bytes = off;
    // --- rest (no init needed) ---
    int*   deg   = (int*)alloc(N_NODES * sizeof(int));
    int*   gp    = (int*)alloc((NUM_GRAPHS + 1) * sizeof(int));
    int*   bsum  = (int*)alloc(256 * sizeof(int));
    int*   rowp  = (int*)alloc((N_NODES + 1) * sizeof(int));
    int*   bh    = (int*)alloc(NBLK * 64 * sizeof(int));
    unsigned short* pos  = (unsigned short*)alloc(N_EDGES * sizeof(unsigned short));
    unsigned short* csr  = (unsigned short*)alloc(N_EDGES * sizeof(unsigned short));
    unsigned short* perm = (unsigned short*)alloc(N_NODES * sizeof(unsigned short));
    const size_t NBH = (size_t)N_NODES * D * sizeof(unsigned short);
    unsigned short* xb   = (unsigned short*)alloc(NBH);
    unsigned short* bufA = (unsigned short*)alloc(NBH);
    unsigned short* bufB = (unsigned short*)alloc(NBH);
    unsigned short* bufC = (unsigned short*)alloc(NBH);
    short8* Wb   = (short8*)alloc(6 * 32 * 64 * sizeof(short8));
    // ph scratch aliases bufB (6.4 MB < 12.8 MB); last use (k_scatter) precedes bufB's first write
    unsigned short* ph = (unsigned short*)bufB;

    hipMemsetAsync(ws, 0, zero_bytes, stream);

    k_ph<<<dim3(CHUNKS, RANGES), 256, 0, stream>>>(dst, pos, ph);
    k_m1<<<NBLK, 256, 0, stream>>>(ph, bat, deg, bsum, gp, bh);
    k_xw<<<3125, 256, 0, stream>>>(x, W1, W2, (us4*)xb, Wb);
    k_s2<<<1, 256, 0, stream>>>(bsum, rowp, bh);
    k_s3<<<NBLK, 256, 0, stream>>>(deg, bsum, rowp, bh, perm);
    k_scatter<<<(N_EDGES / 4 + 255) / 256, 256, 0, stream>>>(src, dst, pos, ph, rowp, csr);

    const int agg_grid  = N_NODES * 16 / 256;     // 3125
    const int gemm_grid = (N_NODES + 127) / 128;  // 391
    const unsigned short* H = xb;
    for (int i = 0; i < NLAYERS; i++) {
        float* st1 = stats + (size_t)(2 * i) * SBANKS * 2 * D;
        float* st2 = stats + (size_t)(2 * i + 1) * SBANKS * 2 * D;
        float* st2p = stats + (size_t)(2 * i - 1) * SBANKS * 2 * D;  // prev layer bn2
        if (i == 0)
            k_agg<false><<<agg_grid, 256, 0, stream>>>((const us8*)H, nullptr, nullptr, nullptr,
                                                       rowp, csr, perm, (us8*)bufA);
        else
            k_agg<true><<<agg_grid, 256, 0, stream>>>((const us8*)H, st2p, g2 + (i - 1) * D,
                                                      bt2 + (i - 1) * D, rowp, csr, perm, (us8*)bufA);
        k_gemm<false><<<gemm_grid, 256, 0, stream>>>(bufA, Wb + (size_t)i * 2048, b1 + i * D,
                                                     nullptr, nullptr, nullptr, bufB, st1, N_NODES);
        k_gemm<true><<<gemm_grid, 256, 0, stream>>>(bufB, Wb + (size_t)(3 + i) * 2048, b2 + i * D,
                                                    st1, g1 + i * D, bt1 + i * D, bufC, st2, N_NODES);
        k_readout<<<NBLK, 256, 0, stream>>>((const unsigned int*)bufC, st2, g2 + i * D, bt2 + i * D,
                                            gp, bat, ro, i);
        H = bufC;
    }
    k_cls<<<NUM_GRAPHS, 128, 0, stream>>>(ro, Wc1, bc1, Wc2, bc2, out);
}